// Round 17
// baseline (134.950 us; speedup 1.0000x reference)
//
#include <hip/hip_runtime.h>
#include <math.h>

#define T_BINS 350
#define REF_LEN 32
#define NB 32
#define NPIX 3072
#define N1 240
#define N2 10
#define NVAL 256
#define WROW 256                  // padded row width (floats) in W
#define WROWS (NVAL + 1)          // 256 value rows + 1 zero row
#define CH 35                     // chunk length (350 = 10*35)  [R17: was 50]
#define NCHUNK 10
#define NTHREADS 576              // 9 waves: 4 L1 + 4 u2 (2 items/lane) + 1 L2

// ---------------------------------------------------------------------------
// Kernel 1 (fused): blocks 0..31 -> per-batch CSR build; blocks 32..223 ->
// 64x64 tiled transpose of w1; block 224 -> inverse bin map inv[t]=v or -1.
// (unchanged, proven)
// ---------------------------------------------------------------------------
__global__ void prep(const int* __restrict__ inp,
                     int* __restrict__ pix,    // [NB][NPIX]
                     int* __restrict__ offs,   // [NB][NVAL]
                     int* __restrict__ cnts,   // [NB][NVAL]
                     const float* __restrict__ w1,
                     float* __restrict__ w1t,
                     const int* __restrict__ table,
                     int* __restrict__ inv)    // [T_BINS]
{
    __shared__ int lc[NVAL];
    __shared__ int ls[NVAL];
    __shared__ int lslot[NVAL];
    __shared__ float tile[64][65];
    __shared__ int linv[T_BINS];

    const int tid = threadIdx.x;

    if (blockIdx.x < NB) {
        // ---- CSR build for batch b ----
        const int b = blockIdx.x;
        lc[tid] = 0;
        __syncthreads();

        int vals[12];
        #pragma unroll
        for (int i = 0; i < 12; ++i) {
            int v = inp[b * NPIX + i * 256 + tid];   // coalesced
            vals[i] = v;
            atomicAdd(&lc[v], 1);
        }
        __syncthreads();

        int x = lc[tid];
        ls[tid] = x;
        __syncthreads();
        for (int d = 1; d < 256; d <<= 1) {
            int y = (tid >= d) ? ls[tid - d] : 0;
            __syncthreads();
            ls[tid] += y;
            __syncthreads();
        }
        int excl = ls[tid] - x;
        offs[b * NVAL + tid] = excl;
        cnts[b * NVAL + tid] = x;
        lslot[tid] = excl;
        __syncthreads();

        #pragma unroll
        for (int i = 0; i < 12; ++i) {
            int slot = atomicAdd(&lslot[vals[i]], 1);
            pix[b * NPIX + slot] = i * 256 + tid;
        }
    } else if (blockIdx.x < NB + 192) {
        // ---- transpose tile ----
        const int tt = blockIdx.x - NB;       // 0..191
        const int p0 = (tt % 48) * 64;
        const int n0 = (tt / 48) * 64;
        const int c  = tid & 63;
        const int r0 = tid >> 6;              // 0..3

        #pragma unroll
        for (int i = 0; i < 16; ++i) {
            int n = n0 + r0 + i * 4;
            if (n < N1) tile[r0 + i * 4][c] = w1[n * NPIX + p0 + c];
        }
        __syncthreads();
        #pragma unroll
        for (int i = 0; i < 16; ++i) {
            int p = p0 + r0 + i * 4;
            int n = n0 + c;
            if (n < N1) w1t[p * N1 + n] = tile[c][r0 + i * 4];
        }
    } else {
        // ---- inverse bin map (table is injective value->bin) ----
        for (int i = tid; i < T_BINS; i += 256) linv[i] = -1;
        __syncthreads();
        if (tid < NVAL) linv[table[tid]] = tid;
        __syncthreads();
        for (int i = tid; i < T_BINS; i += 256) inv[i] = linv[i];
    }
}

// ---------------------------------------------------------------------------
// Kernel 2: W[b][v][n] = sum over pixels with value v of w1t[p, n].
// One value per block (8192 blocks, R11-proven). Padded layout [NB][257][256].
// ---------------------------------------------------------------------------
__global__ void compute_w(const float* __restrict__ w1t,
                          const int* __restrict__ pix,
                          const int* __restrict__ offs,
                          const int* __restrict__ cnts,
                          float* __restrict__ W)     // [NB][WROWS][WROW]
{
    const int v   = blockIdx.x;
    const int b   = blockIdx.y;
    const int tid = threadIdx.x;

    float outv = 0.0f;
    if (tid < N1) {
        const int cnt = cnts[b * NVAL + v];
        const int* pl = pix + b * NPIX + offs[b * NVAL + v];
        double acc = 0.0;
        int i = 0;
        for (; i + 4 <= cnt; i += 4) {
            int p0 = pl[i], p1 = pl[i + 1], p2 = pl[i + 2], p3 = pl[i + 3];
            double w0  = (double)w1t[p0 * N1 + tid];
            double w1v = (double)w1t[p1 * N1 + tid];
            double w2v = (double)w1t[p2 * N1 + tid];
            double w3  = (double)w1t[p3 * N1 + tid];
            acc += w0; acc += w1v; acc += w2v; acc += w3;   // ascending order
        }
        for (; i < cnt; ++i)
            acc += (double)w1t[pl[i] * N1 + tid];
        outv = (float)acc;
    }
    W[((size_t)b * WROWS + v) * WROW + tid] = outv;
    // zero row (v = NVAL) for empty time bins, once per batch
    if (v == 0)
        W[((size_t)b * WROWS + NVAL) * WROW + tid] = 0.0f;
}

// ---------------------------------------------------------------------------
// Dynamics math (identical constants/ops to all prior rounds).
// ---------------------------------------------------------------------------
#define DYN_CONSTS \
    const double A    = 0.9048374180359595;     \
    const double C    = 0.2718281828459045;     \
    const double Ar   = 0.36787944117144233;    \
    const double Cr   = -54.365636569180904;    \
    const double C31A = 1.0671679036256927e-12; \
    const double C31B = 3.4424771084699765e-14;

#define DYN_CORE(uin)                                         \
        q = A * (q + p);                                      \
        p = A * p + (uin);                                    \
        double vm = C * q + Cr * Q;                           \
        unsigned int sb = (vm >= 10.0) ? 1u : 0u;             \
        double s = (double)sb;                                \
        double sel31 = (hist & 0x80000000u) ? C31A : 0.0;     \
        double sel30 = (hist & 0x40000000u) ? C31B : 0.0;     \
        Q = Ar * (Q + P - sel31);                             \
        P = s + (Ar * P - sel30);                             \
        hist = (hist << 1) | sb;

// expand M(i) for i = 0..34
#define F35(M) M(0) M(1) M(2) M(3) M(4) M(5) M(6) M(7) M(8) M(9) \
               M(10) M(11) M(12) M(13) M(14) M(15) M(16) M(17) M(18) M(19) \
               M(20) M(21) M(22) M(23) M(24) M(25) M(26) M(27) M(28) M(29) \
               M(30) M(31) M(32) M(33) M(34)

// ---------------------------------------------------------------------------
// Kernel 3 (pipelined fusion). R17: CH 50->35 (iterations 9->12).
// Calibrated model (fits R8=62.2 and R15=49.0 exactly):
//   time = (NCHUNK+2)*f + (350+2*CH)*s,  f=1.34us/iter, s=0.069us/step.
// R16 (CH=50) predicted 43.2 but measured 52.0 with WRITE_SIZE 438->1106KB:
// 100 named floats exceeded the 84-VGPR allocator ceiling and SPILLED.
// CH=35 needs 70 floats (~78 VGPR) — under the ceiling — and predicts
// 45.1us. Spill indicator to check: WRITE_SIZE must stay ~438KB.
// 9 waves: 0-3 layer-1, 4-7 u2 (350 items, 2 reps/lane), 8 layer-2.
// Same per-element math/order/rounding -> absmax 0.0.
// ---------------------------------------------------------------------------
__global__ __launch_bounds__(NTHREADS, 1) void fused_dyn(
        const float* __restrict__ W,     // [NB][WROWS][WROW]
        const int* __restrict__ inv,     // [T_BINS]
        const float* __restrict__ w2,    // [N2][N1]
        float* __restrict__ out)         // [NB][N2][T_BINS]
{
    __shared__ unsigned long long mbuf[2][CH][4];   // 2.2 KB
    __shared__ float u2buf[2][CH][11];              // 3.1 KB (pad 11)
    __shared__ float sout[T_BINS][11];              // 15.4 KB (pad 11)
    __shared__ float lw2[N2][N1 + 1];               // 9.6 KB (pad 241)
    __shared__ int loff[T_BINS];                    // 1.4 KB

    const int tid  = threadIdx.x;
    const int b    = blockIdx.x;
    const int wid  = tid >> 6;
    const int lane = tid & 63;

    for (int i = tid; i < N2 * N1; i += NTHREADS) lw2[i / N1][i % N1] = w2[i];
    for (int i = tid; i < T_BINS; i += NTHREADS) {
        int v = inv[i];
        loff[i] = ((v >= 0) ? v : NVAL) * (WROW * 4);
    }
    __syncthreads();

    DYN_CONSTS
    double p = 0.0, q = 0.0, P = 0.0, Q = 0.0;   // IIR state: L1 (waves 0-3)
    unsigned int hist = 0u;                       // or L2 (wave 8, lane<10)

    // stage-1 prefetch state: named scalars, never an indexable object
#define DECL_CF(i) float c##i = 0.0f, f##i = 0.0f;
    F35(DECL_CF)

    const char* wb = nullptr;
    if (wid < 4) {
        const int n = wid * 64 + lane;            // 0..255, legal (padded) col
        wb = (const char*)W + ((size_t)b * WROWS) * (WROW * 4) + (size_t)n * 4;
#define LOADC(i) c##i = *(const float*)(wb + loff[i]);
        F35(LOADC)
    }

    for (int it = 0; it < NCHUNK + 2; ++it) {
        if (wid < 4 && it < NCHUNK) {
            // ---- stage 1: layer-1 dynamics, chunk it ----
            if (it + 1 < NCHUNK) {
                const int base = (it + 1) * CH;
#define LOADF(i) f##i = *(const float*)(wb + loff[base + i]);
                F35(LOADF)
            }
            const int slot = it & 1;
#define STEP1(i) { DYN_CORE((double)c##i)                                  \
                   unsigned long long msk = __ballot(sb != 0u);            \
                   if (lane == 0) mbuf[slot][i][wid] = msk; }
            F35(STEP1)
            asm volatile("" : "+v"(f0), "+v"(f1), "+v"(f2), "+v"(f3),
                              "+v"(f4), "+v"(f5), "+v"(f6), "+v"(f7),
                              "+v"(f8), "+v"(f9), "+v"(f10), "+v"(f11));
            asm volatile("" : "+v"(f12), "+v"(f13), "+v"(f14), "+v"(f15),
                              "+v"(f16), "+v"(f17), "+v"(f18), "+v"(f19),
                              "+v"(f20), "+v"(f21), "+v"(f22), "+v"(f23));
            asm volatile("" : "+v"(f24), "+v"(f25), "+v"(f26), "+v"(f27),
                              "+v"(f28), "+v"(f29), "+v"(f30), "+v"(f31),
                              "+v"(f32), "+v"(f33), "+v"(f34));
#define COPYC(i) c##i = f##i;
            F35(COPYC)
        } else if (wid >= 4 && wid < 8 && it >= 1 && it <= NCHUNK) {
            // ---- stage 2: u2 for chunk it-1; 2 items per lane ----
            const int slot = (it - 1) & 1;
            const int base_item = (wid - 4) * 64 + lane;   // 0..255
            #pragma unroll
            for (int rep = 0; rep < 2; ++rep) {
                const int item = base_item + rep * 256;    // 0..511, need 350
                if (item < CH * N2) {
                    const int st = item / N2;
                    const int m  = item - st * N2;
                    double acc = 0.0;
                    #pragma unroll
                    for (int kk = 0; kk < 4; ++kk) {
                        unsigned long long msk = mbuf[slot][st][kk];
                        while (msk) {
                            int j = __ffsll(msk) - 1;
                            acc += (double)lw2[m][kk * 64 + j];
                            msk &= msk - 1;
                        }
                    }
                    u2buf[slot][st][m] = (float)acc;
                }
            }
        } else if (wid == 8 && lane < N2 && it >= 2) {
            // ---- stage 3: layer-2 IIR, chunk it-2 ----
            const int cl = it - 2;
            const int slot = cl & 1;
            const int m = lane;
            const int tb = cl * CH;
#define DECL_G(i) float g##i = u2buf[slot][i][m];
            F35(DECL_G)
            asm volatile("" : "+v"(g0), "+v"(g1), "+v"(g2), "+v"(g3),
                              "+v"(g4), "+v"(g5), "+v"(g6), "+v"(g7),
                              "+v"(g8), "+v"(g9), "+v"(g10), "+v"(g11));
            asm volatile("" : "+v"(g12), "+v"(g13), "+v"(g14), "+v"(g15),
                              "+v"(g16), "+v"(g17), "+v"(g18), "+v"(g19),
                              "+v"(g20), "+v"(g21), "+v"(g22), "+v"(g23));
            asm volatile("" : "+v"(g24), "+v"(g25), "+v"(g26), "+v"(g27),
                              "+v"(g28), "+v"(g29), "+v"(g30), "+v"(g31),
                              "+v"(g32), "+v"(g33), "+v"(g34));
#define STEP3(i) { DYN_CORE((double)g##i) sout[tb + i][m] = (float)s; }
            F35(STEP3)
        }
        __syncthreads();
    }

    // ---- coalesced output out[b][m][t] ----
    float* ob = out + (size_t)b * N2 * T_BINS;
    for (int id = tid; id < N2 * T_BINS; id += NTHREADS) {
        const int m = id / T_BINS;
        const int t = id - m * T_BINS;
        ob[id] = sout[t][m];
    }
}

// ---------------------------------------------------------------------------
extern "C" void kernel_launch(void* const* d_in, const int* in_sizes, int n_in,
                              void* d_out, int out_size, void* d_ws, size_t ws_size,
                              hipStream_t stream) {
    const int*   inp   = (const int*)d_in[0];    // [32,3,32,32]
    const int*   table = (const int*)d_in[1];    // [256]
    const float* w1    = (const float*)d_in[2];  // [240,3072]
    const float* w2    = (const float*)d_in[3];  // [10,240]
    float* out = (float*)d_out;                  // [32,10,350]

    char* ws = (char*)d_ws;
    size_t off = 0;
    float* W   = (float*)(ws + off);  off += (size_t)NB * WROWS * WROW * 4;  // 8.4 MB
    float* w1t = (float*)(ws + off);  off += (size_t)NPIX * N1 * 4;          // 2.9 MB
    int*   pix = (int*)(ws + off);    off += (size_t)NB * NPIX * 4;
    int*  offs = (int*)(ws + off);    off += (size_t)NB * NVAL * 4;
    int*  cnts = (int*)(ws + off);    off += (size_t)NB * NVAL * 4;
    int*   inv = (int*)(ws + off);    off += (size_t)T_BINS * 4;

    prep<<<NB + 192 + 1, 256, 0, stream>>>(inp, pix, offs, cnts, w1, w1t, table, inv);
    compute_w<<<dim3(NVAL, NB), 256, 0, stream>>>(w1t, pix, offs, cnts, W);
    fused_dyn<<<NB, NTHREADS, 0, stream>>>(W, inv, w2, out);
}

// Round 18
// 127.021 us; speedup vs baseline: 1.0624x; 1.0624x over previous
//
#include <hip/hip_runtime.h>
#include <math.h>

#define T_BINS 350
#define REF_LEN 32
#define NB 32
#define NPIX 3072
#define N1 240
#define N2 10
#define NVAL 256
#define WROW 256                  // padded row width (floats) in W
#define WROWS (NVAL + 1)          // 256 value rows + 1 zero row
#define CH 35                     // chunk length (350 = 10*35)
#define NCHUNK 10
#define NTHREADS 704              // 11 waves: 4 L1 + 6 u2 (1 item/lane) + 1 L2

// ---------------------------------------------------------------------------
// Kernel 1 (fused): blocks 0..31 -> per-batch CSR build; blocks 32..223 ->
// 64x64 tiled transpose of w1; block 224 -> inverse bin map inv[t]=v or -1.
// (unchanged, proven)
// ---------------------------------------------------------------------------
__global__ void prep(const int* __restrict__ inp,
                     int* __restrict__ pix,    // [NB][NPIX]
                     int* __restrict__ offs,   // [NB][NVAL]
                     int* __restrict__ cnts,   // [NB][NVAL]
                     const float* __restrict__ w1,
                     float* __restrict__ w1t,
                     const int* __restrict__ table,
                     int* __restrict__ inv)    // [T_BINS]
{
    __shared__ int lc[NVAL];
    __shared__ int ls[NVAL];
    __shared__ int lslot[NVAL];
    __shared__ float tile[64][65];
    __shared__ int linv[T_BINS];

    const int tid = threadIdx.x;

    if (blockIdx.x < NB) {
        // ---- CSR build for batch b ----
        const int b = blockIdx.x;
        lc[tid] = 0;
        __syncthreads();

        int vals[12];
        #pragma unroll
        for (int i = 0; i < 12; ++i) {
            int v = inp[b * NPIX + i * 256 + tid];   // coalesced
            vals[i] = v;
            atomicAdd(&lc[v], 1);
        }
        __syncthreads();

        int x = lc[tid];
        ls[tid] = x;
        __syncthreads();
        for (int d = 1; d < 256; d <<= 1) {
            int y = (tid >= d) ? ls[tid - d] : 0;
            __syncthreads();
            ls[tid] += y;
            __syncthreads();
        }
        int excl = ls[tid] - x;
        offs[b * NVAL + tid] = excl;
        cnts[b * NVAL + tid] = x;
        lslot[tid] = excl;
        __syncthreads();

        #pragma unroll
        for (int i = 0; i < 12; ++i) {
            int slot = atomicAdd(&lslot[vals[i]], 1);
            pix[b * NPIX + slot] = i * 256 + tid;
        }
    } else if (blockIdx.x < NB + 192) {
        // ---- transpose tile ----
        const int tt = blockIdx.x - NB;       // 0..191
        const int p0 = (tt % 48) * 64;
        const int n0 = (tt / 48) * 64;
        const int c  = tid & 63;
        const int r0 = tid >> 6;              // 0..3

        #pragma unroll
        for (int i = 0; i < 16; ++i) {
            int n = n0 + r0 + i * 4;
            if (n < N1) tile[r0 + i * 4][c] = w1[n * NPIX + p0 + c];
        }
        __syncthreads();
        #pragma unroll
        for (int i = 0; i < 16; ++i) {
            int p = p0 + r0 + i * 4;
            int n = n0 + c;
            if (n < N1) w1t[p * N1 + n] = tile[c][r0 + i * 4];
        }
    } else {
        // ---- inverse bin map (table is injective value->bin) ----
        for (int i = tid; i < T_BINS; i += 256) linv[i] = -1;
        __syncthreads();
        if (tid < NVAL) linv[table[tid]] = tid;
        __syncthreads();
        for (int i = tid; i < T_BINS; i += 256) inv[i] = linv[i];
    }
}

// ---------------------------------------------------------------------------
// Kernel 2: W[b][v][n] = sum over pixels with value v of w1t[p, n].
// One value per block (8192 blocks, R11-proven). Padded layout [NB][257][256].
// ---------------------------------------------------------------------------
__global__ void compute_w(const float* __restrict__ w1t,
                          const int* __restrict__ pix,
                          const int* __restrict__ offs,
                          const int* __restrict__ cnts,
                          float* __restrict__ W)     // [NB][WROWS][WROW]
{
    const int v   = blockIdx.x;
    const int b   = blockIdx.y;
    const int tid = threadIdx.x;

    float outv = 0.0f;
    if (tid < N1) {
        const int cnt = cnts[b * NVAL + v];
        const int* pl = pix + b * NPIX + offs[b * NVAL + v];
        double acc = 0.0;
        int i = 0;
        for (; i + 4 <= cnt; i += 4) {
            int p0 = pl[i], p1 = pl[i + 1], p2 = pl[i + 2], p3 = pl[i + 3];
            double w0  = (double)w1t[p0 * N1 + tid];
            double w1v = (double)w1t[p1 * N1 + tid];
            double w2v = (double)w1t[p2 * N1 + tid];
            double w3  = (double)w1t[p3 * N1 + tid];
            acc += w0; acc += w1v; acc += w2v; acc += w3;   // ascending order
        }
        for (; i < cnt; ++i)
            acc += (double)w1t[pl[i] * N1 + tid];
        outv = (float)acc;
    }
    W[((size_t)b * WROWS + v) * WROW + tid] = outv;
    // zero row (v = NVAL) for empty time bins, once per batch
    if (v == 0)
        W[((size_t)b * WROWS + NVAL) * WROW + tid] = 0.0f;
}

// ---------------------------------------------------------------------------
// Dynamics math (identical constants/ops to all prior rounds).
// ---------------------------------------------------------------------------
#define DYN_CONSTS \
    const double A    = 0.9048374180359595;     \
    const double C    = 0.2718281828459045;     \
    const double Ar   = 0.36787944117144233;    \
    const double Cr   = -54.365636569180904;    \
    const double C31A = 1.0671679036256927e-12; \
    const double C31B = 3.4424771084699765e-14;

#define DYN_CORE(uin)                                         \
        q = A * (q + p);                                      \
        p = A * p + (uin);                                    \
        double vm = C * q + Cr * Q;                           \
        unsigned int sb = (vm >= 10.0) ? 1u : 0u;             \
        double s = (double)sb;                                \
        double sel31 = (hist & 0x80000000u) ? C31A : 0.0;     \
        double sel30 = (hist & 0x40000000u) ? C31B : 0.0;     \
        Q = Ar * (Q + P - sel31);                             \
        P = s + (Ar * P - sel30);                             \
        hist = (hist << 1) | sb;

// expand M(i) for i = 0..34
#define F35(M) M(0) M(1) M(2) M(3) M(4) M(5) M(6) M(7) M(8) M(9) \
               M(10) M(11) M(12) M(13) M(14) M(15) M(16) M(17) M(18) M(19) \
               M(20) M(21) M(22) M(23) M(24) M(25) M(26) M(27) M(28) M(29) \
               M(30) M(31) M(32) M(33) M(34)

// ---------------------------------------------------------------------------
// Kernel 3 (pipelined fusion). R18: CH=35 with 6 u2 waves (384 lanes >= 350
// items) so stage 2 stays at 1 ITEM PER LANE. Refined model from the 4
// measured points (R8/R15/R16/R17):
//   time = iters * (f + max(stage1: CH*0.068, stage2: reps*1.7)), f~1.3us
// R17's regression (54.9 vs predicted 45.1) was the reps 1->2 jump at 256
// u2-lanes: body/iter 3.06->4.58us. With 384 lanes reps=1, body = stage1 =
// 2.4us, f grows only ~0.11 (measured ~0.055us/wave): predict ~46us.
// NOT R10's failed redistribution: per-lane unit stays the proven simple
// 1-item walk (R15 structure); only the lane pool matches the item count.
// 11 waves (704 thr): 0-3 L1, 4-9 u2, 10 L2. Same math/order/rounding ->
// absmax 0.0. Spill check: WRITE_SIZE must stay ~438KB (VGPR ~72, R17).
// ---------------------------------------------------------------------------
__global__ __launch_bounds__(NTHREADS, 1) void fused_dyn(
        const float* __restrict__ W,     // [NB][WROWS][WROW]
        const int* __restrict__ inv,     // [T_BINS]
        const float* __restrict__ w2,    // [N2][N1]
        float* __restrict__ out)         // [NB][N2][T_BINS]
{
    __shared__ unsigned long long mbuf[2][CH][4];   // 2.2 KB
    __shared__ float u2buf[2][CH][11];              // 3.1 KB (pad 11)
    __shared__ float sout[T_BINS][11];              // 15.4 KB (pad 11)
    __shared__ float lw2[N2][N1 + 1];               // 9.6 KB (pad 241)
    __shared__ int loff[T_BINS];                    // 1.4 KB

    const int tid  = threadIdx.x;
    const int b    = blockIdx.x;
    const int wid  = tid >> 6;
    const int lane = tid & 63;

    for (int i = tid; i < N2 * N1; i += NTHREADS) lw2[i / N1][i % N1] = w2[i];
    for (int i = tid; i < T_BINS; i += NTHREADS) {
        int v = inv[i];
        loff[i] = ((v >= 0) ? v : NVAL) * (WROW * 4);
    }
    __syncthreads();

    DYN_CONSTS
    double p = 0.0, q = 0.0, P = 0.0, Q = 0.0;   // IIR state: L1 (waves 0-3)
    unsigned int hist = 0u;                       // or L2 (wave 10, lane<10)

    // stage-1 prefetch state: named scalars, never an indexable object
#define DECL_CF(i) float c##i = 0.0f, f##i = 0.0f;
    F35(DECL_CF)

    const char* wb = nullptr;
    if (wid < 4) {
        const int n = wid * 64 + lane;            // 0..255, legal (padded) col
        wb = (const char*)W + ((size_t)b * WROWS) * (WROW * 4) + (size_t)n * 4;
#define LOADC(i) c##i = *(const float*)(wb + loff[i]);
        F35(LOADC)
    }

    for (int it = 0; it < NCHUNK + 2; ++it) {
        if (wid < 4 && it < NCHUNK) {
            // ---- stage 1: layer-1 dynamics, chunk it ----
            if (it + 1 < NCHUNK) {
                const int base = (it + 1) * CH;
#define LOADF(i) f##i = *(const float*)(wb + loff[base + i]);
                F35(LOADF)
            }
            const int slot = it & 1;
#define STEP1(i) { DYN_CORE((double)c##i)                                  \
                   unsigned long long msk = __ballot(sb != 0u);            \
                   if (lane == 0) mbuf[slot][i][wid] = msk; }
            F35(STEP1)
            asm volatile("" : "+v"(f0), "+v"(f1), "+v"(f2), "+v"(f3),
                              "+v"(f4), "+v"(f5), "+v"(f6), "+v"(f7),
                              "+v"(f8), "+v"(f9), "+v"(f10), "+v"(f11));
            asm volatile("" : "+v"(f12), "+v"(f13), "+v"(f14), "+v"(f15),
                              "+v"(f16), "+v"(f17), "+v"(f18), "+v"(f19),
                              "+v"(f20), "+v"(f21), "+v"(f22), "+v"(f23));
            asm volatile("" : "+v"(f24), "+v"(f25), "+v"(f26), "+v"(f27),
                              "+v"(f28), "+v"(f29), "+v"(f30), "+v"(f31),
                              "+v"(f32), "+v"(f33), "+v"(f34));
#define COPYC(i) c##i = f##i;
            F35(COPYC)
        } else if (wid >= 4 && wid < 10 && it >= 1 && it <= NCHUNK) {
            // ---- stage 2: u2 for chunk it-1; ONE item per lane ----
            const int item = (wid - 4) * 64 + lane;   // 0..383, need 350
            if (item < CH * N2) {
                const int st = item / N2;
                const int m  = item - st * N2;
                const int slot = (it - 1) & 1;
                double acc = 0.0;
                #pragma unroll
                for (int kk = 0; kk < 4; ++kk) {
                    unsigned long long msk = mbuf[slot][st][kk];
                    while (msk) {
                        int j = __ffsll(msk) - 1;
                        acc += (double)lw2[m][kk * 64 + j];
                        msk &= msk - 1;
                    }
                }
                u2buf[slot][st][m] = (float)acc;
            }
        } else if (wid == 10 && lane < N2 && it >= 2) {
            // ---- stage 3: layer-2 IIR, chunk it-2 ----
            const int cl = it - 2;
            const int slot = cl & 1;
            const int m = lane;
            const int tb = cl * CH;
#define DECL_G(i) float g##i = u2buf[slot][i][m];
            F35(DECL_G)
            asm volatile("" : "+v"(g0), "+v"(g1), "+v"(g2), "+v"(g3),
                              "+v"(g4), "+v"(g5), "+v"(g6), "+v"(g7),
                              "+v"(g8), "+v"(g9), "+v"(g10), "+v"(g11));
            asm volatile("" : "+v"(g12), "+v"(g13), "+v"(g14), "+v"(g15),
                              "+v"(g16), "+v"(g17), "+v"(g18), "+v"(g19),
                              "+v"(g20), "+v"(g21), "+v"(g22), "+v"(g23));
            asm volatile("" : "+v"(g24), "+v"(g25), "+v"(g26), "+v"(g27),
                              "+v"(g28), "+v"(g29), "+v"(g30), "+v"(g31),
                              "+v"(g32), "+v"(g33), "+v"(g34));
#define STEP3(i) { DYN_CORE((double)g##i) sout[tb + i][m] = (float)s; }
            F35(STEP3)
        }
        __syncthreads();
    }

    // ---- coalesced output out[b][m][t] ----
    float* ob = out + (size_t)b * N2 * T_BINS;
    for (int id = tid; id < N2 * T_BINS; id += NTHREADS) {
        const int m = id / T_BINS;
        const int t = id - m * T_BINS;
        ob[id] = sout[t][m];
    }
}

// ---------------------------------------------------------------------------
extern "C" void kernel_launch(void* const* d_in, const int* in_sizes, int n_in,
                              void* d_out, int out_size, void* d_ws, size_t ws_size,
                              hipStream_t stream) {
    const int*   inp   = (const int*)d_in[0];    // [32,3,32,32]
    const int*   table = (const int*)d_in[1];    // [256]
    const float* w1    = (const float*)d_in[2];  // [240,3072]
    const float* w2    = (const float*)d_in[3];  // [10,240]
    float* out = (float*)d_out;                  // [32,10,350]

    char* ws = (char*)d_ws;
    size_t off = 0;
    float* W   = (float*)(ws + off);  off += (size_t)NB * WROWS * WROW * 4;  // 8.4 MB
    float* w1t = (float*)(ws + off);  off += (size_t)NPIX * N1 * 4;          // 2.9 MB
    int*   pix = (int*)(ws + off);    off += (size_t)NB * NPIX * 4;
    int*  offs = (int*)(ws + off);    off += (size_t)NB * NVAL * 4;
    int*  cnts = (int*)(ws + off);    off += (size_t)NB * NVAL * 4;
    int*   inv = (int*)(ws + off);    off += (size_t)T_BINS * 4;

    prep<<<NB + 192 + 1, 256, 0, stream>>>(inp, pix, offs, cnts, w1, w1t, table, inv);
    compute_w<<<dim3(NVAL, NB), 256, 0, stream>>>(w1t, pix, offs, cnts, W);
    fused_dyn<<<NB, NTHREADS, 0, stream>>>(W, inv, w2, out);
}